// Round 1
// baseline (622.697 us; speedup 1.0000x reference)
//
#include <hip/hip_runtime.h>
#include <math.h>

#define N 1024
#define C 81
#define F 1024
#define K 100
#define NC1 80              // C-1 foreground classes
#define MAXC (NC1 * N)      // candidate capacity 81920

#define SCORE_THRESH 0.05f
#define NMS_THRESH   0.5f
#define BBOX_CLIP    4.135166556742356f   // log(1000/16)
#define IMG_W1       1215.0f              // IMG_W - 1
#define IMG_H1       799.0f               // IMG_H - 1

// ---------------- init: zero candidate counter, invalidate selection slots --
__global__ void k_init(int* counter, float* sel_score) {
    int t = threadIdx.x;
    if (t == 0) *counter = 0;
    if (t < K) sel_score[t] = -1.0f;
}

// ---------------- softmax over classes + box decode + clip -----------------
// one block per proposal row
__global__ __launch_bounds__(128) void k_softmax_decode(
    const float* __restrict__ logits, const float* __restrict__ boxreg,
    const float* __restrict__ pboxes, float* __restrict__ probs,
    float4* __restrict__ dec)
{
    int n = blockIdx.x, t = threadIdx.x;
    __shared__ float red[128];

    float v = (t < C) ? logits[n * C + t] : -INFINITY;
    red[t] = v; __syncthreads();
    for (int s = 64; s > 0; s >>= 1) { if (t < s) red[t] = fmaxf(red[t], red[t + s]); __syncthreads(); }
    float mx = red[0]; __syncthreads();

    float e = (t < C) ? expf(v - mx) : 0.0f;
    red[t] = e; __syncthreads();
    for (int s = 64; s > 0; s >>= 1) { if (t < s) red[t] += red[t + s]; __syncthreads(); }
    float sum = red[0];

    if (t < C) {
        probs[n * C + t] = e / sum;

        float bx1 = pboxes[n * 4 + 0], by1 = pboxes[n * 4 + 1];
        float bx2 = pboxes[n * 4 + 2], by2 = pboxes[n * 4 + 3];
        float w  = bx2 - bx1 + 1.0f, h = by2 - by1 + 1.0f;
        float cx = bx1 + 0.5f * w,  cy = by1 + 0.5f * h;

        const float* r = boxreg + (size_t)n * (C * 4) + t * 4;
        float dx = r[0] / 10.0f, dy = r[1] / 10.0f;
        float dw = fminf(r[2] / 5.0f, BBOX_CLIP);
        float dh = fminf(r[3] / 5.0f, BBOX_CLIP);

        float pcx = dx * w + cx, pcy = dy * h + cy;
        float pw = expf(dw) * w, ph = expf(dh) * h;

        float x1 = pcx - 0.5f * pw,        y1 = pcy - 0.5f * ph;
        float x2 = pcx + 0.5f * pw - 1.0f, y2 = pcy + 0.5f * ph - 1.0f;

        x1 = fminf(fmaxf(x1, 0.0f), IMG_W1);
        y1 = fminf(fmaxf(y1, 0.0f), IMG_H1);
        x2 = fminf(fmaxf(x2, 0.0f), IMG_W1);
        y2 = fminf(fmaxf(y2, 0.0f), IMG_H1);

        dec[n * C + t] = make_float4(x1, y1, x2, y2);
    }
}

// ---------------- per-class: sort (desc, stable) + sequential NMS + compact -
// one block per foreground class; 32KB LDS
__global__ __launch_bounds__(256) void k_nms(
    const float* __restrict__ probs, const float4* __restrict__ dec,
    int* counter, float* __restrict__ cscore, int* __restrict__ cflat,
    int* __restrict__ corig, float4* __restrict__ cbox)
{
    int c = blockIdx.x;            // class index-1 (label = c+1)
    int t = threadIdx.x;
    __shared__ float  skey[N];
    __shared__ int    sidx[N];
    __shared__ float4 sbox[N];
    __shared__ float  sarea[N];
    __shared__ int    skeep[N];
    __shared__ int    sV;

    for (int p = t; p < N; p += 256) {
        float s = probs[p * C + (c + 1)];
        skey[p] = (s > SCORE_THRESH) ? s : -INFINITY;
        sidx[p] = p;
    }
    __syncthreads();

    // bitonic sort: descending score, ties -> ascending original index
    // (matches stable jnp.argsort(-s))
    for (int k = 2; k <= N; k <<= 1) {
        for (int j = k >> 1; j > 0; j >>= 1) {
            for (int i = t; i < N; i += 256) {
                int ixj = i ^ j;
                if (ixj > i) {
                    float s1 = skey[i], s2 = skey[ixj];
                    int   i1 = sidx[i], i2 = sidx[ixj];
                    bool before = (s1 > s2) || (s1 == s2 && i1 < i2); // i belongs before ixj
                    bool desc   = ((i & k) == 0);
                    if (desc ? !before : before) {
                        skey[i] = s2; skey[ixj] = s1;
                        sidx[i] = i2; sidx[ixj] = i1;
                    }
                }
            }
            __syncthreads();
        }
    }

    if (t == 0) sV = N;
    __syncthreads();
    for (int p = t; p < N; p += 256) {
        int o = sidx[p];
        float4 b = dec[o * C + (c + 1)];
        sbox[p]  = b;
        sarea[p] = (b.z - b.x + 1.0f) * (b.w - b.y + 1.0f);
        bool valid = skey[p] > -INFINITY;
        skeep[p] = valid ? 1 : 0;
        if (!valid) atomicMin(&sV, p);
    }
    __syncthreads();
    int V = sV;

    // sequential suppression: only still-kept i suppresses j > i
    for (int i = 0; i < V; ++i) {
        if (skeep[i]) {            // wave-uniform branch
            float4 bi = sbox[i];
            float  ai = sarea[i];
            for (int j = i + 1 + t; j < V; j += 256) {
                if (skeep[j]) {
                    float4 bj = sbox[j];
                    float lx = fmaxf(bi.x, bj.x), ly = fmaxf(bi.y, bj.y);
                    float rx = fminf(bi.z, bj.z), ry = fminf(bi.w, bj.w);
                    float ww = fmaxf(rx - lx + 1.0f, 0.0f);
                    float hh = fmaxf(ry - ly + 1.0f, 0.0f);
                    float inter = ww * hh;
                    float iou = inter / (ai + sarea[j] - inter); // 0/0=NaN -> not >0.5, matches jnp
                    if (iou > NMS_THRESH) skeep[j] = 0;
                }
            }
        }
        __syncthreads();
    }

    // compact kept candidates
    for (int p = t; p < V; p += 256) {
        if (skeep[p]) {
            int pos = atomicAdd(counter, 1);
            cscore[pos] = skey[p];
            cflat[pos]  = c * N + p;     // flat idx in s_kept.reshape(-1)
            corig[pos]  = sidx[p];
            cbox[pos]   = sbox[p];
        }
    }
}

// ---------------- exact top-K by rank over (score desc, flat asc) ----------
__global__ __launch_bounds__(256) void k_topk(
    const int* __restrict__ counter, const float* __restrict__ cscore,
    const int* __restrict__ cflat, float* __restrict__ sel_score,
    int* __restrict__ sel_idx)
{
    int M = *counter;
    int p = blockIdx.x * blockDim.x + threadIdx.x;
    if (p >= M) return;
    float sp = cscore[p];
    int   fp = cflat[p];
    int rank = 0;
    for (int q = 0; q < M; ++q) {
        float sq = cscore[q];
        if (sq > sp || (sq == sp && cflat[q] < fp)) {
            if (++rank >= K) return;   // can no longer be selected
        }
    }
    sel_score[rank] = sp;
    sel_idx[rank]   = p;
}

// ---------------- gather outputs ------------------------------------------
// out layout: boxes[K*4] | scores[K] | feats[K*F] | labels[K]  (all f32)
__global__ __launch_bounds__(256) void k_gather(
    const float* __restrict__ sel_score, const int* __restrict__ sel_idx,
    const int* __restrict__ cflat, const int* __restrict__ corig,
    const float4* __restrict__ cbox, const float* __restrict__ feats,
    float* __restrict__ out)
{
    int k = blockIdx.x, t = threadIdx.x;
    float s = sel_score[k];
    bool ok = s > 0.0f;
    float4 b = make_float4(0.f, 0.f, 0.f, 0.f);
    int label = 0, orig = 0;
    if (ok) {
        int ci = sel_idx[k];
        b     = cbox[ci];
        label = (cflat[ci] >> 10) + 1;   // cls = flat / N, N=1024
        orig  = corig[ci];
    }
    if (t == 0) {
        out[k * 4 + 0] = b.x; out[k * 4 + 1] = b.y;
        out[k * 4 + 2] = b.z; out[k * 4 + 3] = b.w;
        out[K * 4 + k] = ok ? s : 0.0f;
        out[K * 4 + K + K * F + k] = (float)label;
    }
    const float* src = feats + (size_t)orig * F;
    float* dst = out + K * 4 + K + (size_t)k * F;
    for (int f = t; f < F; f += 256) dst[f] = ok ? src[f] : 0.0f;
}

// ---------------------------------------------------------------------------
extern "C" void kernel_launch(void* const* d_in, const int* in_sizes, int n_in,
                              void* d_out, int out_size, void* d_ws, size_t ws_size,
                              hipStream_t stream)
{
    const float* logits = (const float*)d_in[0];   // [N,C]
    const float* boxreg = (const float*)d_in[1];   // [N,C*4]
    const float* pboxes = (const float*)d_in[2];   // [N,4]
    const float* feats  = (const float*)d_in[3];   // [N,F]
    float* out = (float*)d_out;

    char* ws = (char*)d_ws;
    size_t off = 0;
    auto alloc = [&](size_t bytes) {
        size_t cur = off;
        off = (off + bytes + 255) & ~(size_t)255;
        return cur;
    };
    int*    counter   = (int*)   (ws + alloc(sizeof(int)));
    float*  probs     = (float*) (ws + alloc(sizeof(float)  * N * C));
    float4* dec       = (float4*)(ws + alloc(sizeof(float4) * N * C));
    float*  cscore    = (float*) (ws + alloc(sizeof(float)  * MAXC));
    int*    cflat     = (int*)   (ws + alloc(sizeof(int)    * MAXC));
    int*    corig     = (int*)   (ws + alloc(sizeof(int)    * MAXC));
    float4* cbox      = (float4*)(ws + alloc(sizeof(float4) * MAXC));
    float*  sel_score = (float*) (ws + alloc(sizeof(float)  * K));
    int*    sel_idx   = (int*)   (ws + alloc(sizeof(int)    * K));

    hipLaunchKernelGGL(k_init, dim3(1), dim3(128), 0, stream, counter, sel_score);
    hipLaunchKernelGGL(k_softmax_decode, dim3(N), dim3(128), 0, stream,
                       logits, boxreg, pboxes, probs, dec);
    hipLaunchKernelGGL(k_nms, dim3(NC1), dim3(256), 0, stream,
                       probs, dec, counter, cscore, cflat, corig, cbox);
    hipLaunchKernelGGL(k_topk, dim3((MAXC + 255) / 256), dim3(256), 0, stream,
                       counter, cscore, cflat, sel_score, sel_idx);
    hipLaunchKernelGGL(k_gather, dim3(K), dim3(256), 0, stream,
                       sel_score, sel_idx, cflat, corig, cbox, feats, out);
}

// Round 2
// 326.620 us; speedup vs baseline: 1.9065x; 1.9065x over previous
//
#include <hip/hip_runtime.h>
#include <math.h>

#define N 1024
#define C 81
#define F 1024
#define K 100
#define NC1 80              // C-1 foreground classes
#define MAXC (NC1 * N)      // candidate capacity 81920

#define SCORE_THRESH 0.05f
#define NMS_THRESH   0.5f
#define BBOX_CLIP    4.135166556742356f   // log(1000/16)
#define IMG_W1       1215.0f              // IMG_W - 1
#define IMG_H1       799.0f               // IMG_H - 1

// ---------------- init: zero candidate counter ------------------------------
__global__ void k_init(int* counter) {
    if (threadIdx.x == 0) *counter = 0;
}

// ---------------- softmax over classes + box decode + clip -----------------
// one block per proposal row
__global__ __launch_bounds__(128) void k_softmax_decode(
    const float* __restrict__ logits, const float* __restrict__ boxreg,
    const float* __restrict__ pboxes, float* __restrict__ probs,
    float4* __restrict__ dec)
{
    int n = blockIdx.x, t = threadIdx.x;
    __shared__ float red[128];

    float v = (t < C) ? logits[n * C + t] : -INFINITY;
    red[t] = v; __syncthreads();
    for (int s = 64; s > 0; s >>= 1) { if (t < s) red[t] = fmaxf(red[t], red[t + s]); __syncthreads(); }
    float mx = red[0]; __syncthreads();

    float e = (t < C) ? expf(v - mx) : 0.0f;
    red[t] = e; __syncthreads();
    for (int s = 64; s > 0; s >>= 1) { if (t < s) red[t] += red[t + s]; __syncthreads(); }
    float sum = red[0];

    if (t < C) {
        probs[n * C + t] = e / sum;

        float bx1 = pboxes[n * 4 + 0], by1 = pboxes[n * 4 + 1];
        float bx2 = pboxes[n * 4 + 2], by2 = pboxes[n * 4 + 3];
        float w  = bx2 - bx1 + 1.0f, h = by2 - by1 + 1.0f;
        float cx = bx1 + 0.5f * w,  cy = by1 + 0.5f * h;

        const float* r = boxreg + (size_t)n * (C * 4) + t * 4;
        float dx = r[0] / 10.0f, dy = r[1] / 10.0f;
        float dw = fminf(r[2] / 5.0f, BBOX_CLIP);
        float dh = fminf(r[3] / 5.0f, BBOX_CLIP);

        float pcx = dx * w + cx, pcy = dy * h + cy;
        float pw = expf(dw) * w, ph = expf(dh) * h;

        float x1 = pcx - 0.5f * pw,        y1 = pcy - 0.5f * ph;
        float x2 = pcx + 0.5f * pw - 1.0f, y2 = pcy + 0.5f * ph - 1.0f;

        x1 = fminf(fmaxf(x1, 0.0f), IMG_W1);
        y1 = fminf(fmaxf(y1, 0.0f), IMG_H1);
        x2 = fminf(fmaxf(x2, 0.0f), IMG_W1);
        y2 = fminf(fmaxf(y2, 0.0f), IMG_H1);

        dec[n * C + t] = make_float4(x1, y1, x2, y2);
    }
}

// ---------------- per-class: sort (desc, stable) + sequential NMS + compact -
// one block per foreground class; ~32KB LDS
// Emits packed sort keys: (score_bits << 32) | ~flat_idx  -- uint64 ordering
// == (score desc, flat asc), exactly lax.top_k's tie-break.
__global__ __launch_bounds__(256) void k_nms(
    const float* __restrict__ probs, const float4* __restrict__ dec,
    int* counter, unsigned long long* __restrict__ ckey,
    int* __restrict__ corig, float4* __restrict__ cbox)
{
    int c = blockIdx.x;            // class index-1 (label = c+1)
    int t = threadIdx.x;
    __shared__ float  skey[N];
    __shared__ int    sidx[N];
    __shared__ float4 sbox[N];
    __shared__ float  sarea[N];
    __shared__ int    skeep[N];
    __shared__ int    sV;

    for (int p = t; p < N; p += 256) {
        float s = probs[p * C + (c + 1)];
        skey[p] = (s > SCORE_THRESH) ? s : -INFINITY;
        sidx[p] = p;
    }
    __syncthreads();

    // bitonic sort: descending score, ties -> ascending original index
    // (matches stable jnp.argsort(-s))
    for (int k = 2; k <= N; k <<= 1) {
        for (int j = k >> 1; j > 0; j >>= 1) {
            for (int i = t; i < N; i += 256) {
                int ixj = i ^ j;
                if (ixj > i) {
                    float s1 = skey[i], s2 = skey[ixj];
                    int   i1 = sidx[i], i2 = sidx[ixj];
                    bool before = (s1 > s2) || (s1 == s2 && i1 < i2); // i belongs before ixj
                    bool desc   = ((i & k) == 0);
                    if (desc ? !before : before) {
                        skey[i] = s2; skey[ixj] = s1;
                        sidx[i] = i2; sidx[ixj] = i1;
                    }
                }
            }
            __syncthreads();
        }
    }

    if (t == 0) sV = N;
    __syncthreads();
    for (int p = t; p < N; p += 256) {
        int o = sidx[p];
        float4 b = dec[o * C + (c + 1)];
        sbox[p]  = b;
        sarea[p] = (b.z - b.x + 1.0f) * (b.w - b.y + 1.0f);
        bool valid = skey[p] > -INFINITY;
        skeep[p] = valid ? 1 : 0;
        if (!valid) atomicMin(&sV, p);
    }
    __syncthreads();
    int V = sV;

    // sequential suppression: only still-kept i suppresses j > i
    for (int i = 0; i < V; ++i) {
        if (skeep[i]) {            // wave-uniform branch
            float4 bi = sbox[i];
            float  ai = sarea[i];
            for (int j = i + 1 + t; j < V; j += 256) {
                if (skeep[j]) {
                    float4 bj = sbox[j];
                    float lx = fmaxf(bi.x, bj.x), ly = fmaxf(bi.y, bj.y);
                    float rx = fminf(bi.z, bj.z), ry = fminf(bi.w, bj.w);
                    float ww = fmaxf(rx - lx + 1.0f, 0.0f);
                    float hh = fmaxf(ry - ly + 1.0f, 0.0f);
                    float inter = ww * hh;
                    float iou = inter / (ai + sarea[j] - inter); // 0/0=NaN -> not >0.5, matches jnp
                    if (iou > NMS_THRESH) skeep[j] = 0;
                }
            }
        }
        __syncthreads();
    }

    // compact kept candidates with packed top-k keys
    for (int p = t; p < V; p += 256) {
        if (skeep[p]) {
            int pos = atomicAdd(counter, 1);
            unsigned int flat = (unsigned)(c * N + p);
            ckey[pos] = ((unsigned long long)__float_as_uint(skey[p]) << 32)
                        | (unsigned long long)(unsigned)(~flat);
            corig[pos] = sidx[p];
            cbox[pos]  = sbox[p];
        }
    }
}

// ---------------- exact top-K: K rounds of block-wide argmax ---------------
// single block, 1024 threads. Destroys ckey (zeroes winners).
__global__ __launch_bounds__(1024) void k_topk(
    const int* __restrict__ counter, unsigned long long* ckey,
    float* __restrict__ sel_score, int* __restrict__ sel_idx,
    int* __restrict__ sel_flat)
{
    int M = *counter;
    int t = threadIdx.x;
    __shared__ unsigned long long wkey[16];
    __shared__ int wpos[16];

    for (int k = 0; k < K; ++k) {
        unsigned long long key = 0ull; int pos = -1;
        for (int p = t; p < M; p += 1024) {
            unsigned long long kk = ckey[p];
            if (kk > key) { key = kk; pos = p; }
        }
        // 64-lane wave argmax
        for (int off = 32; off > 0; off >>= 1) {
            unsigned long long ok = __shfl_down(key, off);
            int op = __shfl_down(pos, off);
            if (ok > key) { key = ok; pos = op; }
        }
        if ((t & 63) == 0) { wkey[t >> 6] = key; wpos[t >> 6] = pos; }
        __syncthreads();
        if (t == 0) {
            for (int w = 1; w < 16; ++w)
                if (wkey[w] > key) { key = wkey[w]; pos = wpos[w]; }
            if (key != 0ull) {
                sel_score[k] = __uint_as_float((unsigned)(key >> 32));
                sel_idx[k]   = pos;
                sel_flat[k]  = (int)(~(unsigned)(key & 0xffffffffu));
                ckey[pos]    = 0ull;          // remove winner
            } else {
                sel_score[k] = -1.0f;
                sel_idx[k]   = -1;
                sel_flat[k]  = 0;
            }
        }
        __syncthreads();   // also fences the ckey[pos]=0 write for next round
    }
}

// ---------------- gather outputs ------------------------------------------
// out layout: boxes[K*4] | scores[K] | feats[K*F] | labels[K]  (all f32)
__global__ __launch_bounds__(256) void k_gather(
    const float* __restrict__ sel_score, const int* __restrict__ sel_idx,
    const int* __restrict__ sel_flat, const int* __restrict__ corig,
    const float4* __restrict__ cbox, const float* __restrict__ feats,
    float* __restrict__ out)
{
    int k = blockIdx.x, t = threadIdx.x;
    float s = sel_score[k];
    bool ok = s > 0.0f;
    float4 b = make_float4(0.f, 0.f, 0.f, 0.f);
    int label = 0, orig = 0;
    if (ok) {
        int ci = sel_idx[k];
        b     = cbox[ci];
        label = (sel_flat[k] >> 10) + 1;   // cls = flat / N, N=1024
        orig  = corig[ci];
    }
    if (t == 0) {
        out[k * 4 + 0] = b.x; out[k * 4 + 1] = b.y;
        out[k * 4 + 2] = b.z; out[k * 4 + 3] = b.w;
        out[K * 4 + k] = ok ? s : 0.0f;
        out[K * 4 + K + K * F + k] = (float)label;
    }
    const float* src = feats + (size_t)orig * F;
    float* dst = out + K * 4 + K + (size_t)k * F;
    for (int f = t; f < F; f += 256) dst[f] = ok ? src[f] : 0.0f;
}

// ---------------------------------------------------------------------------
extern "C" void kernel_launch(void* const* d_in, const int* in_sizes, int n_in,
                              void* d_out, int out_size, void* d_ws, size_t ws_size,
                              hipStream_t stream)
{
    const float* logits = (const float*)d_in[0];   // [N,C]
    const float* boxreg = (const float*)d_in[1];   // [N,C*4]
    const float* pboxes = (const float*)d_in[2];   // [N,4]
    const float* feats  = (const float*)d_in[3];   // [N,F]
    float* out = (float*)d_out;

    char* ws = (char*)d_ws;
    size_t off = 0;
    auto alloc = [&](size_t bytes) {
        size_t cur = off;
        off = (off + bytes + 255) & ~(size_t)255;
        return cur;
    };
    int*    counter   = (int*)   (ws + alloc(sizeof(int)));
    float*  probs     = (float*) (ws + alloc(sizeof(float)  * N * C));
    float4* dec       = (float4*)(ws + alloc(sizeof(float4) * N * C));
    unsigned long long* ckey = (unsigned long long*)(ws + alloc(sizeof(unsigned long long) * MAXC));
    int*    corig     = (int*)   (ws + alloc(sizeof(int)    * MAXC));
    float4* cbox      = (float4*)(ws + alloc(sizeof(float4) * MAXC));
    float*  sel_score = (float*) (ws + alloc(sizeof(float)  * K));
    int*    sel_idx   = (int*)   (ws + alloc(sizeof(int)    * K));
    int*    sel_flat  = (int*)   (ws + alloc(sizeof(int)    * K));

    hipLaunchKernelGGL(k_init, dim3(1), dim3(64), 0, stream, counter);
    hipLaunchKernelGGL(k_softmax_decode, dim3(N), dim3(128), 0, stream,
                       logits, boxreg, pboxes, probs, dec);
    hipLaunchKernelGGL(k_nms, dim3(NC1), dim3(256), 0, stream,
                       probs, dec, counter, ckey, corig, cbox);
    hipLaunchKernelGGL(k_topk, dim3(1), dim3(1024), 0, stream,
                       counter, ckey, sel_score, sel_idx, sel_flat);
    hipLaunchKernelGGL(k_gather, dim3(K), dim3(256), 0, stream,
                       sel_score, sel_idx, sel_flat, corig, cbox, feats, out);
}

// Round 3
// 151.308 us; speedup vs baseline: 4.1154x; 2.1586x over previous
//
#include <hip/hip_runtime.h>
#include <math.h>

#define N 1024
#define C 81
#define F 1024
#define K 100
#define NC1 80              // C-1 foreground classes
#define MAXC (NC1 * N)      // candidate capacity 81920
#define NHIST 32768         // score-bit histogram buckets
#define SELCAP 2048         // LDS select capacity

#define SCORE_THRESH 0.05f
#define NMS_THRESH   0.5f
#define BBOX_CLIP    4.135166556742356f   // log(1000/16)
#define IMG_W1       1215.0f              // IMG_W - 1
#define IMG_H1       799.0f               // IMG_H - 1

// ---------------- init: zero candidate counter + histogram -----------------
__global__ __launch_bounds__(512) void k_init(int* counter, int* hist) {
    int i = blockIdx.x * 512 + threadIdx.x;
    if (i < NHIST) hist[i] = 0;
    if (i == 0) *counter = 0;
}

// ---------------- softmax over classes + box decode + clip -----------------
// one wave per proposal (lane t covers classes t and t+64); no barriers
__global__ __launch_bounds__(256) void k_softmax_decode(
    const float* __restrict__ logits, const float* __restrict__ boxreg,
    const float* __restrict__ pboxes, float* __restrict__ probs,
    float4* __restrict__ dec)
{
    int n = blockIdx.x * 4 + (threadIdx.x >> 6);
    int t = threadIdx.x & 63;

    float v1 = logits[n * C + t];
    float v2 = (t < C - 64) ? logits[n * C + 64 + t] : -INFINITY;
    float m = fmaxf(v1, v2);
    for (int off = 32; off; off >>= 1) m = fmaxf(m, __shfl_xor(m, off));
    float e1 = expf(v1 - m);
    float e2 = (t < C - 64) ? expf(v2 - m) : 0.0f;
    float s = e1 + e2;
    for (int off = 32; off; off >>= 1) s += __shfl_xor(s, off);

    probs[n * C + t] = e1 / s;
    if (t < C - 64) probs[n * C + 64 + t] = e2 / s;

    // proposal box params (same-address loads broadcast)
    float bx1 = pboxes[n * 4 + 0], by1 = pboxes[n * 4 + 1];
    float bx2 = pboxes[n * 4 + 2], by2 = pboxes[n * 4 + 3];
    float w  = bx2 - bx1 + 1.0f, h = by2 - by1 + 1.0f;
    float cx = bx1 + 0.5f * w,  cy = by1 + 0.5f * h;

    #pragma unroll
    for (int rep = 0; rep < 2; ++rep) {
        int cl = t + rep * 64;
        if (cl >= C) break;
        const float* r = boxreg + (size_t)n * (C * 4) + cl * 4;
        float dx = r[0] / 10.0f, dy = r[1] / 10.0f;
        float dw = fminf(r[2] / 5.0f, BBOX_CLIP);
        float dh = fminf(r[3] / 5.0f, BBOX_CLIP);

        float pcx = dx * w + cx, pcy = dy * h + cy;
        float pw = expf(dw) * w, ph = expf(dh) * h;

        float x1 = pcx - 0.5f * pw,        y1 = pcy - 0.5f * ph;
        float x2 = pcx + 0.5f * pw - 1.0f, y2 = pcy + 0.5f * ph - 1.0f;

        x1 = fminf(fmaxf(x1, 0.0f), IMG_W1);
        y1 = fminf(fmaxf(y1, 0.0f), IMG_H1);
        x2 = fminf(fmaxf(x2, 0.0f), IMG_W1);
        y2 = fminf(fmaxf(y2, 0.0f), IMG_H1);

        dec[n * C + cl] = make_float4(x1, y1, x2, y2);
    }
}

// ---------------- per-class: sort (desc, stable) + sequential NMS + compact -
// one block per foreground class; ~32KB LDS
// Emits packed keys (score_bits<<32 | ~flat), a score-bit histogram, and the
// per-class sort permutation corder[c*N+p] = original proposal idx.
__global__ __launch_bounds__(256) void k_nms(
    const float* __restrict__ probs, const float4* __restrict__ dec,
    int* counter, unsigned long long* __restrict__ ckey,
    int* __restrict__ hist, int* __restrict__ corder)
{
    int c = blockIdx.x;            // class index-1 (label = c+1)
    int t = threadIdx.x;
    __shared__ float  skey[N];
    __shared__ int    sidx[N];
    __shared__ float4 sbox[N];
    __shared__ float  sarea[N];
    __shared__ int    skeep[N];
    __shared__ int    sV;

    for (int p = t; p < N; p += 256) {
        float s = probs[p * C + (c + 1)];
        skey[p] = (s > SCORE_THRESH) ? s : -INFINITY;
        sidx[p] = p;
    }
    __syncthreads();

    // bitonic sort: descending score, ties -> ascending original index
    // (matches stable jnp.argsort(-s))
    for (int k = 2; k <= N; k <<= 1) {
        for (int j = k >> 1; j > 0; j >>= 1) {
            for (int i = t; i < N; i += 256) {
                int ixj = i ^ j;
                if (ixj > i) {
                    float s1 = skey[i], s2 = skey[ixj];
                    int   i1 = sidx[i], i2 = sidx[ixj];
                    bool before = (s1 > s2) || (s1 == s2 && i1 < i2);
                    bool desc   = ((i & k) == 0);
                    if (desc ? !before : before) {
                        skey[i] = s2; skey[ixj] = s1;
                        sidx[i] = i2; sidx[ixj] = i1;
                    }
                }
            }
            __syncthreads();
        }
    }

    if (t == 0) sV = N;
    __syncthreads();
    for (int p = t; p < N; p += 256) {
        int o = sidx[p];
        corder[c * N + p] = o;
        float4 b = dec[o * C + (c + 1)];
        sbox[p]  = b;
        sarea[p] = (b.z - b.x + 1.0f) * (b.w - b.y + 1.0f);
        bool valid = skey[p] > -INFINITY;
        skeep[p] = valid ? 1 : 0;
        if (!valid) atomicMin(&sV, p);
    }
    __syncthreads();
    int V = sV;

    // sequential suppression: only still-kept i suppresses j > i
    for (int i = 0; i < V; ++i) {
        if (skeep[i]) {            // wave-uniform branch
            float4 bi = sbox[i];
            float  ai = sarea[i];
            for (int j = i + 1 + t; j < V; j += 256) {
                if (skeep[j]) {
                    float4 bj = sbox[j];
                    float lx = fmaxf(bi.x, bj.x), ly = fmaxf(bi.y, bj.y);
                    float rx = fminf(bi.z, bj.z), ry = fminf(bi.w, bj.w);
                    float ww = fmaxf(rx - lx + 1.0f, 0.0f);
                    float hh = fmaxf(ry - ly + 1.0f, 0.0f);
                    float inter = ww * hh;
                    float iou = inter / (ai + sarea[j] - inter);
                    if (iou > NMS_THRESH) skeep[j] = 0;
                }
            }
        }
        __syncthreads();
    }

    // compact kept candidates: packed key + histogram
    for (int p = t; p < V; p += 256) {
        if (skeep[p]) {
            int pos = atomicAdd(counter, 1);
            unsigned int sb = __float_as_uint(skey[p]);
            unsigned int flat = (unsigned)(c * N + p);
            ckey[pos] = ((unsigned long long)sb << 32)
                        | (unsigned long long)(unsigned)(~flat);
            atomicAdd(&hist[(sb >> 16) & 0x7FFF], 1);
        }
    }
}

// ---------------- exact top-K via radix-select + small bitonic sort --------
// single block, 1024 threads
__global__ __launch_bounds__(1024) void k_select(
    const int* __restrict__ counter, unsigned long long* ckey,
    const int* __restrict__ hist,
    float* __restrict__ sel_score, int* __restrict__ sel_flat)
{
    int t = threadIdx.x;
    __shared__ unsigned long long keys[SELCAP];
    __shared__ int partial[1024];
    __shared__ int sb_bstar, scount;
    __shared__ unsigned long long wk[16];
    __shared__ int wp[16];

    int M = *counter;
    if (t == 0) { sb_bstar = 0; scount = 0; }

    // ---- phase 1: find bucket of the K-th largest key (suffix scan) ----
    int lo = t * 32;
    int h[32];
    int lsum = 0;
    #pragma unroll
    for (int i = 0; i < 32; ++i) { h[i] = hist[lo + i]; lsum += h[i]; }
    partial[t] = lsum;
    __syncthreads();
    for (int off = 1; off < 1024; off <<= 1) {
        int v = partial[t];
        int add = (t + off < 1024) ? partial[t + off] : 0;
        __syncthreads();
        partial[t] = v + add;
        __syncthreads();
    }
    int base = partial[t] - lsum;       // # keys in buckets above my range
    if (base < K && base + lsum >= K) { // crossing is inside my 32 buckets
        int run = base;
        for (int b = 31; b >= 0; --b) {
            int hb = h[b];
            if (run < K && run + hb >= K) { sb_bstar = lo + b; break; }
            run += hb;
        }
    }
    __syncthreads();
    int bstar = sb_bstar;

    // ---- phase 2: compact keys with bucket >= bstar into LDS ----
    for (int p = t; p < M; p += 1024) {
        unsigned long long kk = ckey[p];
        int b = (int)((kk >> 48) & 0x7FFF);
        if (b >= bstar) {
            int pos = atomicAdd(&scount, 1);
            if (pos < SELCAP) keys[pos] = kk;
        }
    }
    __syncthreads();
    int cnt = scount;

    if (cnt > SELCAP) {
        // exact fallback (pathological tie flood): K rounds of argmax
        for (int k = 0; k < K; ++k) {
            unsigned long long key = 0ull; int pos = -1;
            for (int p = t; p < M; p += 1024) {
                unsigned long long kk = ckey[p];
                if (kk > key) { key = kk; pos = p; }
            }
            for (int off = 32; off; off >>= 1) {
                unsigned long long ok2 = __shfl_down(key, off);
                int op = __shfl_down(pos, off);
                if (ok2 > key) { key = ok2; pos = op; }
            }
            if ((t & 63) == 0) { wk[t >> 6] = key; wp[t >> 6] = pos; }
            __syncthreads();
            if (t == 0) {
                for (int w = 1; w < 16; ++w)
                    if (wk[w] > key) { key = wk[w]; pos = wp[w]; }
                if (key != 0ull) {
                    sel_score[k] = __uint_as_float((unsigned)(key >> 32));
                    sel_flat[k]  = (int)(~(unsigned)(key & 0xffffffffu));
                    ckey[pos] = 0ull;
                } else { sel_score[k] = 0.0f; sel_flat[k] = 0; }
            }
            __syncthreads();
        }
        return;
    }

    // ---- phase 3: bitonic sort the padded selection, emit top K ----
    int P = 128;
    while (P < cnt) P <<= 1;
    for (int i = cnt + t; i < P; i += 1024) keys[i] = 0ull;
    __syncthreads();
    for (int k = 2; k <= P; k <<= 1) {
        for (int j = k >> 1; j > 0; j >>= 1) {
            for (int i = t; i < P; i += 1024) {
                int ixj = i ^ j;
                if (ixj > i) {
                    unsigned long long a = keys[i], b = keys[ixj];
                    bool before = a > b;
                    bool desc   = ((i & k) == 0);
                    if (desc ? !before : before) { keys[i] = b; keys[ixj] = a; }
                }
            }
            __syncthreads();
        }
    }
    if (t < K) {
        unsigned long long key = keys[t];
        sel_score[t] = __uint_as_float((unsigned)(key >> 32));
        sel_flat[t]  = (int)(~(unsigned)(key & 0xffffffffu));
    }
}

// ---------------- gather outputs ------------------------------------------
// out layout: boxes[K*4] | scores[K] | feats[K*F] | labels[K]  (all f32)
__global__ __launch_bounds__(256) void k_gather(
    const float* __restrict__ sel_score, const int* __restrict__ sel_flat,
    const int* __restrict__ corder, const float4* __restrict__ dec,
    const float* __restrict__ feats, float* __restrict__ out)
{
    int k = blockIdx.x, t = threadIdx.x;
    float s = sel_score[k];
    bool ok = s > 0.0f;
    float4 b = make_float4(0.f, 0.f, 0.f, 0.f);
    int label = 0, orig = 0;
    if (ok) {
        int flat = sel_flat[k];
        int c = flat >> 10;              // N = 1024
        orig  = corder[flat];
        b     = dec[orig * C + (c + 1)];
        label = c + 1;
    }
    if (t == 0) {
        out[k * 4 + 0] = b.x; out[k * 4 + 1] = b.y;
        out[k * 4 + 2] = b.z; out[k * 4 + 3] = b.w;
        out[K * 4 + k] = ok ? s : 0.0f;
        out[K * 4 + K + K * F + k] = (float)label;
    }
    const float4* src = (const float4*)(feats + (size_t)orig * F);
    float4* dst = (float4*)(out + K * 4 + K + (size_t)k * F);
    float4 z = make_float4(0.f, 0.f, 0.f, 0.f);
    if (t < F / 4) dst[t] = ok ? src[t] : z;
}

// ---------------------------------------------------------------------------
extern "C" void kernel_launch(void* const* d_in, const int* in_sizes, int n_in,
                              void* d_out, int out_size, void* d_ws, size_t ws_size,
                              hipStream_t stream)
{
    const float* logits = (const float*)d_in[0];   // [N,C]
    const float* boxreg = (const float*)d_in[1];   // [N,C*4]
    const float* pboxes = (const float*)d_in[2];   // [N,4]
    const float* feats  = (const float*)d_in[3];   // [N,F]
    float* out = (float*)d_out;

    char* ws = (char*)d_ws;
    size_t off = 0;
    auto alloc = [&](size_t bytes) {
        size_t cur = off;
        off = (off + bytes + 255) & ~(size_t)255;
        return cur;
    };
    int*    counter   = (int*)   (ws + alloc(sizeof(int)));
    float*  probs     = (float*) (ws + alloc(sizeof(float)  * N * C));
    float4* dec       = (float4*)(ws + alloc(sizeof(float4) * N * C));
    unsigned long long* ckey = (unsigned long long*)(ws + alloc(sizeof(unsigned long long) * MAXC));
    int*    hist      = (int*)   (ws + alloc(sizeof(int)    * NHIST));
    int*    corder    = (int*)   (ws + alloc(sizeof(int)    * NC1 * N));
    float*  sel_score = (float*) (ws + alloc(sizeof(float)  * K));
    int*    sel_flat  = (int*)   (ws + alloc(sizeof(int)    * K));

    hipLaunchKernelGGL(k_init, dim3((NHIST + 511) / 512), dim3(512), 0, stream,
                       counter, hist);
    hipLaunchKernelGGL(k_softmax_decode, dim3(N / 4), dim3(256), 0, stream,
                       logits, boxreg, pboxes, probs, dec);
    hipLaunchKernelGGL(k_nms, dim3(NC1), dim3(256), 0, stream,
                       probs, dec, counter, ckey, hist, corder);
    hipLaunchKernelGGL(k_select, dim3(1), dim3(1024), 0, stream,
                       counter, ckey, hist, sel_score, sel_flat);
    hipLaunchKernelGGL(k_gather, dim3(K), dim3(256), 0, stream,
                       sel_score, sel_flat, corder, dec, feats, out);
}

// Round 4
// 106.250 us; speedup vs baseline: 5.8607x; 1.4241x over previous
//
#include <hip/hip_runtime.h>
#include <math.h>

#define N 1024
#define C 81
#define F 1024
#define K 100
#define NC1 80              // C-1 foreground classes
#define MAXC (NC1 * N)      // candidate capacity
#define HBASE 0x3D00        // hist bucket base: float bits >>16 of 0.03125
#define HSIZE 1024          // covers score in (0.05, 1] : buckets 76..640
#define SELCAP 2048         // LDS select capacity

#define SCORE_THRESH 0.05f
#define NMS_THRESH   0.5f
#define BBOX_CLIP    4.135166556742356f   // log(1000/16)
#define IMG_W1       1215.0f
#define IMG_H1       799.0f

typedef unsigned long long u64;
typedef unsigned int u32;

// ---------------- softmax + decode + clip, TRANSPOSED outputs ---------------
// one wave per proposal; also zeroes hist/counter (grid covers HSIZE threads)
__global__ __launch_bounds__(256) void k_softmax_decode(
    const float* __restrict__ logits, const float* __restrict__ boxreg,
    const float* __restrict__ pboxes, float* __restrict__ probsT,
    float4* __restrict__ decT, int* __restrict__ hist, int* __restrict__ counter)
{
    int gid = blockIdx.x * 256 + threadIdx.x;
    if (gid < HSIZE) hist[gid] = 0;
    if (gid == 0) *counter = 0;

    int n = blockIdx.x * 4 + (threadIdx.x >> 6);
    int t = threadIdx.x & 63;

    float v1 = logits[n * C + t];
    float v2 = (t < C - 64) ? logits[n * C + 64 + t] : -INFINITY;
    float m = fmaxf(v1, v2);
    for (int off = 32; off; off >>= 1) m = fmaxf(m, __shfl_xor(m, off));
    float e1 = expf(v1 - m);
    float e2 = (t < C - 64) ? expf(v2 - m) : 0.0f;
    float s = e1 + e2;
    for (int off = 32; off; off >>= 1) s += __shfl_xor(s, off);

    probsT[t * N + n] = e1 / s;
    if (t < C - 64) probsT[(64 + t) * N + n] = e2 / s;

    float bx1 = pboxes[n * 4 + 0], by1 = pboxes[n * 4 + 1];
    float bx2 = pboxes[n * 4 + 2], by2 = pboxes[n * 4 + 3];
    float w  = bx2 - bx1 + 1.0f, h = by2 - by1 + 1.0f;
    float cx = bx1 + 0.5f * w,  cy = by1 + 0.5f * h;

    #pragma unroll
    for (int rep = 0; rep < 2; ++rep) {
        int cl = t + rep * 64;
        if (cl >= C) break;
        const float* r = boxreg + (size_t)n * (C * 4) + cl * 4;
        float dx = r[0] / 10.0f, dy = r[1] / 10.0f;
        float dw = fminf(r[2] / 5.0f, BBOX_CLIP);
        float dh = fminf(r[3] / 5.0f, BBOX_CLIP);

        float pcx = dx * w + cx, pcy = dy * h + cy;
        float pw = expf(dw) * w, ph = expf(dh) * h;

        float x1 = pcx - 0.5f * pw,        y1 = pcy - 0.5f * ph;
        float x2 = pcx + 0.5f * pw - 1.0f, y2 = pcy + 0.5f * ph - 1.0f;

        x1 = fminf(fmaxf(x1, 0.0f), IMG_W1);
        y1 = fminf(fmaxf(y1, 0.0f), IMG_H1);
        x2 = fminf(fmaxf(x2, 0.0f), IMG_W1);
        y2 = fminf(fmaxf(y2, 0.0f), IMG_H1);

        decT[(size_t)cl * N + n] = make_float4(x1, y1, x2, y2);
    }
}

// ---------------- per-class: compact -> sort V -> sequential NMS ------------
// one block per foreground class. Fast path (V<=64): single-wave shuffle
// bitonic + shuffle-broadcast NMS, no barriers. Fallback: LDS bitonic on
// next-pow2(V). Compaction preserves index order; key=(score_bits<<32)|~idx
// so descending-key sort == stable argsort(-score) restricted to valid rows.
__global__ __launch_bounds__(256) void k_nms(
    const float* __restrict__ probsT, const float4* __restrict__ decT,
    int* counter, u64* __restrict__ ckey, int* __restrict__ hist,
    int* __restrict__ corder)
{
    int c = blockIdx.x;            // foreground class (label = c+1)
    int t = threadIdx.x;
    __shared__ u64    skey64[N];
    __shared__ int    scnt[256];
    __shared__ float4 sbox[N];
    __shared__ float  sarea[N];
    __shared__ int    skeep[N];

    // coalesced load of 4 consecutive scores + order-preserving compaction
    const float4* prow = (const float4*)(probsT + (size_t)(c + 1) * N);
    float4 s4 = prow[t];
    int f0 = s4.x > SCORE_THRESH, f1 = s4.y > SCORE_THRESH;
    int f2 = s4.z > SCORE_THRESH, f3 = s4.w > SCORE_THRESH;
    int mycount = f0 + f1 + f2 + f3;
    scnt[t] = mycount;
    __syncthreads();
    for (int off = 1; off < 256; off <<= 1) {
        int v = scnt[t];
        int a = (t >= off) ? scnt[t - off] : 0;
        __syncthreads();
        scnt[t] = v + a;
        __syncthreads();
    }
    int base = scnt[t] - mycount;
    int V = scnt[255];
    {
        int p0 = t * 4, pos = base;
        if (f0) skey64[pos++] = ((u64)__float_as_uint(s4.x) << 32) | (u32)~(u32)(p0);
        if (f1) skey64[pos++] = ((u64)__float_as_uint(s4.y) << 32) | (u32)~(u32)(p0 + 1);
        if (f2) skey64[pos++] = ((u64)__float_as_uint(s4.z) << 32) | (u32)~(u32)(p0 + 2);
        if (f3) skey64[pos++] = ((u64)__float_as_uint(s4.w) << 32) | (u32)~(u32)(p0 + 3);
    }
    __syncthreads();
    if (V == 0) return;

    if (V <= 64) {
        if (t < 64) {
            int lane = t;
            u64 key = (lane < V) ? skey64[lane] : 0ull;
            // descending bitonic over 64 lanes (keys unique; 0-pad sinks)
            for (int k = 2; k <= 64; k <<= 1) {
                for (int j = k >> 1; j > 0; j >>= 1) {
                    u64 other = __shfl_xor(key, j);
                    bool takeMax = (((lane & j) == 0) == ((lane & k) == 0));
                    bool gt = key > other;
                    key = (takeMax == gt) ? key : other;
                }
            }
            bool act = key != 0ull;
            float4 b = make_float4(0.f, 0.f, 0.f, 0.f);
            float area = 0.0f;
            if (act) {
                int idx = (int)(~(u32)(key & 0xffffffffu));
                corder[c * N + lane] = idx;
                b = decT[(size_t)(c + 1) * N + idx];
                area = (b.z - b.x + 1.0f) * (b.w - b.y + 1.0f);
            }
            int kept = act ? 1 : 0;
            for (int i = 0; i + 1 < V; ++i) {
                int   ki  = __shfl(kept, i);
                float bix = __shfl(b.x, i), biy = __shfl(b.y, i);
                float biz = __shfl(b.z, i), biw = __shfl(b.w, i);
                float ai  = __shfl(area, i);
                if (ki && lane > i && kept) {
                    float lx = fmaxf(bix, b.x), ly = fmaxf(biy, b.y);
                    float rx = fminf(biz, b.z), ry = fminf(biw, b.w);
                    float ww = fmaxf(rx - lx + 1.0f, 0.0f);
                    float hh = fmaxf(ry - ly + 1.0f, 0.0f);
                    float inter = ww * hh;
                    float iou = inter / (ai + area - inter);
                    if (iou > NMS_THRESH) kept = 0;
                }
            }
            if (kept) {
                int pos = atomicAdd(counter, 1);
                u32 sb = (u32)(key >> 32);
                ckey[pos] = ((u64)sb << 32) | (u64)(u32)~(u32)(c * N + lane);
                atomicAdd(&hist[(int)(sb >> 16) - HBASE], 1);
            }
        }
        return;
    }

    // ---------- fallback: V > 64, LDS bitonic on P = next pow2 ----------
    int P = 128;
    while (P < V) P <<= 1;
    for (int i = V + t; i < P; i += 256) skey64[i] = 0ull;
    __syncthreads();
    for (int k = 2; k <= P; k <<= 1) {
        for (int j = k >> 1; j > 0; j >>= 1) {
            for (int i = t; i < P; i += 256) {
                int ixj = i ^ j;
                if (ixj > i) {
                    u64 a = skey64[i], bb = skey64[ixj];
                    bool desc = ((i & k) == 0);
                    if (desc ? (a < bb) : (a > bb)) { skey64[i] = bb; skey64[ixj] = a; }
                }
            }
            __syncthreads();
        }
    }
    for (int p = t; p < V; p += 256) {
        int idx = (int)(~(u32)(skey64[p] & 0xffffffffu));
        corder[c * N + p] = idx;
        float4 b = decT[(size_t)(c + 1) * N + idx];
        sbox[p]  = b;
        sarea[p] = (b.z - b.x + 1.0f) * (b.w - b.y + 1.0f);
        skeep[p] = 1;
    }
    __syncthreads();
    for (int i = 0; i < V; ++i) {
        if (skeep[i]) {
            float4 bi = sbox[i];
            float  ai = sarea[i];
            for (int j = i + 1 + t; j < V; j += 256) {
                if (skeep[j]) {
                    float4 bj = sbox[j];
                    float lx = fmaxf(bi.x, bj.x), ly = fmaxf(bi.y, bj.y);
                    float rx = fminf(bi.z, bj.z), ry = fminf(bi.w, bj.w);
                    float ww = fmaxf(rx - lx + 1.0f, 0.0f);
                    float hh = fmaxf(ry - ly + 1.0f, 0.0f);
                    float inter = ww * hh;
                    float iou = inter / (ai + sarea[j] - inter);
                    if (iou > NMS_THRESH) skeep[j] = 0;
                }
            }
        }
        __syncthreads();
    }
    for (int p = t; p < V; p += 256) {
        if (skeep[p]) {
            int pos = atomicAdd(counter, 1);
            u32 sb = (u32)(skey64[p] >> 32);
            ckey[pos] = ((u64)sb << 32) | (u64)(u32)~(u32)(c * N + p);
            atomicAdd(&hist[(int)(sb >> 16) - HBASE], 1);
        }
    }
}

// ---------------- exact top-K via radix-select + small bitonic sort --------
__global__ __launch_bounds__(1024) void k_select(
    const int* __restrict__ counter, u64* ckey, const int* __restrict__ hist,
    float* __restrict__ sel_score, int* __restrict__ sel_flat)
{
    int t = threadIdx.x;
    __shared__ u64 keys[SELCAP];
    __shared__ int partial[1024];
    __shared__ int sb_bstar, scount;
    __shared__ u64 wk[16];
    __shared__ int wp[16];

    int M = *counter;
    if (t == 0) { sb_bstar = 0; scount = 0; }

    // phase 1: suffix scan of 1024-bucket histogram -> bucket of K-th key
    int lsum = hist[t];
    partial[t] = lsum;
    __syncthreads();
    for (int off = 1; off < 1024; off <<= 1) {
        int v = partial[t];
        int a = (t + off < 1024) ? partial[t + off] : 0;
        __syncthreads();
        partial[t] = v + a;
        __syncthreads();
    }
    int base = partial[t] - lsum;              // keys in buckets above t
    if (base < K && base + lsum >= K) sb_bstar = t;
    __syncthreads();
    int bstar = sb_bstar;

    // phase 2: compact keys with bucket >= bstar
    for (int p = t; p < M; p += 1024) {
        u64 kk = ckey[p];
        int b = (int)((kk >> 48) & 0xFFFF) - HBASE;
        if (b >= bstar) {
            int pos = atomicAdd(&scount, 1);
            if (pos < SELCAP) keys[pos] = kk;
        }
    }
    __syncthreads();
    int cnt = scount;

    if (cnt > SELCAP) {
        // exact fallback (tie flood): K rounds of argmax
        for (int k = 0; k < K; ++k) {
            u64 key = 0ull; int pos = -1;
            for (int p = t; p < M; p += 1024) {
                u64 kk = ckey[p];
                if (kk > key) { key = kk; pos = p; }
            }
            for (int off = 32; off; off >>= 1) {
                u64 ok2 = __shfl_down(key, off);
                int op = __shfl_down(pos, off);
                if (ok2 > key) { key = ok2; pos = op; }
            }
            if ((t & 63) == 0) { wk[t >> 6] = key; wp[t >> 6] = pos; }
            __syncthreads();
            if (t == 0) {
                for (int w = 1; w < 16; ++w)
                    if (wk[w] > key) { key = wk[w]; pos = wp[w]; }
                if (key != 0ull) {
                    sel_score[k] = __uint_as_float((u32)(key >> 32));
                    sel_flat[k]  = (int)(~(u32)(key & 0xffffffffu));
                    ckey[pos] = 0ull;
                } else { sel_score[k] = 0.0f; sel_flat[k] = 0; }
            }
            __syncthreads();
        }
        return;
    }

    // phase 3: bitonic sort padded selection, emit top K
    int P = 128;
    while (P < cnt) P <<= 1;
    for (int i = cnt + t; i < P; i += 1024) keys[i] = 0ull;
    __syncthreads();
    for (int k = 2; k <= P; k <<= 1) {
        for (int j = k >> 1; j > 0; j >>= 1) {
            for (int i = t; i < P; i += 1024) {
                int ixj = i ^ j;
                if (ixj > i) {
                    u64 a = keys[i], b = keys[ixj];
                    bool desc = ((i & k) == 0);
                    if (desc ? (a < b) : (a > b)) { keys[i] = b; keys[ixj] = a; }
                }
            }
            __syncthreads();
        }
    }
    if (t < K) {
        u64 key = keys[t];
        sel_score[t] = __uint_as_float((u32)(key >> 32));
        sel_flat[t]  = (int)(~(u32)(key & 0xffffffffu));
    }
}

// ---------------- gather outputs ------------------------------------------
// out layout: boxes[K*4] | scores[K] | feats[K*F] | labels[K]  (all f32)
__global__ __launch_bounds__(256) void k_gather(
    const float* __restrict__ sel_score, const int* __restrict__ sel_flat,
    const int* __restrict__ corder, const float4* __restrict__ decT,
    const float* __restrict__ feats, float* __restrict__ out)
{
    int k = blockIdx.x, t = threadIdx.x;
    float s = sel_score[k];
    bool ok = s > 0.0f;
    float4 b = make_float4(0.f, 0.f, 0.f, 0.f);
    int label = 0, orig = 0;
    if (ok) {
        int flat = sel_flat[k];
        int c = flat >> 10;              // N = 1024
        orig  = corder[flat];
        b     = decT[(size_t)(c + 1) * N + orig];
        label = c + 1;
    }
    if (t == 0) {
        out[k * 4 + 0] = b.x; out[k * 4 + 1] = b.y;
        out[k * 4 + 2] = b.z; out[k * 4 + 3] = b.w;
        out[K * 4 + k] = ok ? s : 0.0f;
        out[K * 4 + K + K * F + k] = (float)label;
    }
    const float4* src = (const float4*)(feats + (size_t)orig * F);
    float4* dst = (float4*)(out + K * 4 + K + (size_t)k * F);
    float4 z = make_float4(0.f, 0.f, 0.f, 0.f);
    if (t < F / 4) dst[t] = ok ? src[t] : z;
}

// ---------------------------------------------------------------------------
extern "C" void kernel_launch(void* const* d_in, const int* in_sizes, int n_in,
                              void* d_out, int out_size, void* d_ws, size_t ws_size,
                              hipStream_t stream)
{
    const float* logits = (const float*)d_in[0];   // [N,C]
    const float* boxreg = (const float*)d_in[1];   // [N,C*4]
    const float* pboxes = (const float*)d_in[2];   // [N,4]
    const float* feats  = (const float*)d_in[3];   // [N,F]
    float* out = (float*)d_out;

    char* ws = (char*)d_ws;
    size_t off = 0;
    auto alloc = [&](size_t bytes) {
        size_t cur = off;
        off = (off + bytes + 255) & ~(size_t)255;
        return cur;
    };
    int*    counter   = (int*)   (ws + alloc(sizeof(int)));
    float*  probsT    = (float*) (ws + alloc(sizeof(float)  * C * N));
    float4* decT      = (float4*)(ws + alloc(sizeof(float4) * C * N));
    u64*    ckey      = (u64*)   (ws + alloc(sizeof(u64)    * MAXC));
    int*    hist      = (int*)   (ws + alloc(sizeof(int)    * HSIZE));
    int*    corder    = (int*)   (ws + alloc(sizeof(int)    * NC1 * N));
    float*  sel_score = (float*) (ws + alloc(sizeof(float)  * K));
    int*    sel_flat  = (int*)   (ws + alloc(sizeof(int)    * K));

    hipLaunchKernelGGL(k_softmax_decode, dim3(N / 4), dim3(256), 0, stream,
                       logits, boxreg, pboxes, probsT, decT, hist, counter);
    hipLaunchKernelGGL(k_nms, dim3(NC1), dim3(256), 0, stream,
                       probsT, decT, counter, ckey, hist, corder);
    hipLaunchKernelGGL(k_select, dim3(1), dim3(1024), 0, stream,
                       counter, ckey, hist, sel_score, sel_flat);
    hipLaunchKernelGGL(k_gather, dim3(K), dim3(256), 0, stream,
                       sel_score, sel_flat, corder, decT, feats, out);
}